// Round 2
// 1566.127 us; speedup vs baseline: 1.1210x; 1.1210x over previous
//
#include <hip/hip_runtime.h>
#include <hip/hip_bf16.h>
#include <cstdint>
#include <cstddef>

#define DEV __device__ __forceinline__

constexpr int Bb = 2, Ls = 4096, Dd = 2048, Hh = 32, HD = 64, MBK = 16, NMBc = 256;
constexpr int MTOK = Bb * Ls; // 8192 tokens

typedef __bf16 bf16x8 __attribute__((ext_vector_type(8)));
typedef float  f32x4  __attribute__((ext_vector_type(4)));

DEV unsigned short f2bf(float f) {
    union { float f; unsigned int u; } x; x.f = f;
    unsigned int u = x.u;
    return (unsigned short)((u + 0x7fffu + ((u >> 16) & 1u)) >> 16);
}
DEV float b2f(unsigned short u) {
    union { unsigned int i; float f; } x; x.i = ((unsigned int)u) << 16;
    return x.f;
}

// 64-lane sum via DPP (no LDS round-trips; ~50cy vs ~700cy for ds_swizzle butterfly).
// row_shr 1/2/4/8 accumulate within each row of 16 (bound_ctrl=1 -> OOB reads 0),
// row_bcast15 folds row0->row1 / row2->row3 (row_mask 0xa),
// row_bcast31 folds rows01->rows23 (row_mask 0xc); lane 63 holds the total,
// readlane broadcasts it uniformly (all call sites need a uniform value).
DEV float wsum64(float v) {
    int t;
    t = __builtin_amdgcn_update_dpp(0, __float_as_int(v), 0x111, 0xf, 0xf, true); v += __int_as_float(t);
    t = __builtin_amdgcn_update_dpp(0, __float_as_int(v), 0x112, 0xf, 0xf, true); v += __int_as_float(t);
    t = __builtin_amdgcn_update_dpp(0, __float_as_int(v), 0x114, 0xf, 0xf, true); v += __int_as_float(t);
    t = __builtin_amdgcn_update_dpp(0, __float_as_int(v), 0x118, 0xf, 0xf, true); v += __int_as_float(t);
    t = __builtin_amdgcn_update_dpp(0, __float_as_int(v), 0x142, 0xa, 0xf, true); v += __int_as_float(t);
    t = __builtin_amdgcn_update_dpp(0, __float_as_int(v), 0x143, 0xc, 0xf, true); v += __int_as_float(t);
    return __int_as_float(__builtin_amdgcn_readlane(__float_as_int(v), 63));
}

DEV void g2l16(const void* g, void* l) {
    __builtin_amdgcn_global_load_lds(
        (__attribute__((address_space(1))) void*)(g),
        (__attribute__((address_space(3))) void*)(l), 16, 0, 0);
}

// ---------------- cast hidden_states fp32 -> bf16 ----------------
__global__ __launch_bounds__(256) void cast_hs_kernel(const float* __restrict__ src,
                                                      unsigned short* __restrict__ dst) {
    int i = (blockIdx.x * 256 + threadIdx.x) * 4;
    float4 v = *(const float4*)(src + i);
    ushort4 o; o.x = f2bf(v.x); o.y = f2bf(v.y); o.z = f2bf(v.z); o.w = f2bf(v.w);
    *(ushort4*)(dst + i) = o;
}

// ---------------- transpose + cast weight: W[k][n] fp32 -> Wt[n][k] bf16 ----------------
__global__ __launch_bounds__(256) void transpose_cast_kernel(const float* __restrict__ W,
                                                             unsigned short* __restrict__ Wt) {
    __shared__ float tile[64][65];
    int bx = blockIdx.x & 31;   // k-tile
    int by = blockIdx.x >> 5;   // n-tile
    int t = threadIdx.x;
    int r = t >> 4, c4 = (t & 15) * 4;
    #pragma unroll
    for (int i = 0; i < 4; ++i) {
        int row = r + i * 16;
        float4 v = *(const float4*)(W + (size_t)(bx * 64 + row) * Dd + by * 64 + c4);
        tile[row][c4 + 0] = v.x; tile[row][c4 + 1] = v.y;
        tile[row][c4 + 2] = v.z; tile[row][c4 + 3] = v.w;
    }
    __syncthreads();
    #pragma unroll
    for (int i = 0; i < 4; ++i) {
        int row = r + i * 16; // n index
        ushort4 o;
        o.x = f2bf(tile[c4 + 0][row]); o.y = f2bf(tile[c4 + 1][row]);
        o.z = f2bf(tile[c4 + 2][row]); o.w = f2bf(tile[c4 + 3][row]);
        *(ushort4*)(Wt + (size_t)(by * 64 + row) * Dd + bx * 64 + c4) = o;
    }
}

// ---------------- bf16 MFMA GEMM:  C[M,N] = A[M,K] @ Bt[N,K]^T + bias ----------------
__global__ __launch_bounds__(256) void gemm_bt_kernel(const unsigned short* __restrict__ A,
                                                      const unsigned short* __restrict__ Bt,
                                                      const float* __restrict__ bias,
                                                      float* __restrict__ C,
                                                      int M, int N, int Kd) {
    __shared__ unsigned short sA[128 * 64];
    __shared__ unsigned short sB[128 * 64];
    int t = threadIdx.x;
    int lane = t & 63;
    int wid = t >> 6, wm = wid >> 1, wn = wid & 1;
    int quad = lane >> 4, c = lane & 15;
    int bm = blockIdx.x, bn = blockIdx.y;

    const unsigned short* pa[4]; const unsigned short* pb[4];
    unsigned short* la[4]; unsigned short* lb[4];
    #pragma unroll
    for (int i = 0; i < 4; ++i) {
        int lin = i * 256 + t;
        int row = lin >> 3, blk = lin & 7;
        int oct = blk ^ (row & 7);
        pa[i] = A  + (size_t)(bm * 128 + row) * Kd + oct * 8;
        pb[i] = Bt + (size_t)(bn * 128 + row) * Kd + oct * 8;
        la[i] = sA + lin * 8;
        lb[i] = sB + lin * 8;
    }

    f32x4 acc[4][4];
    #pragma unroll
    for (int i = 0; i < 4; ++i)
        #pragma unroll
        for (int j = 0; j < 4; ++j)
            #pragma unroll
            for (int r = 0; r < 4; ++r) acc[i][j][r] = 0.f;

    const char* sAc = (const char*)sA;
    const char* sBc = (const char*)sB;
    int rowA0 = wm * 64 + c, rowB0 = wn * 64 + c;
    int sw = (c & 7);

    int nkt = Kd >> 6;
    for (int kt = 0; kt < nkt; ++kt) {
        #pragma unroll
        for (int i = 0; i < 4; ++i) {
            g2l16(pa[i], la[i]);
            g2l16(pb[i], lb[i]);
            pa[i] += 64; pb[i] += 64;
        }
        __syncthreads();
        #pragma unroll
        for (int s = 0; s < 2; ++s) {
            bf16x8 af[4], bfv[4];
            int so = (s << 2) | quad;
            #pragma unroll
            for (int mt = 0; mt < 4; ++mt)
                af[mt] = *(const bf16x8*)(sAc + (rowA0 + mt * 16) * 128 + ((so ^ sw) * 16));
            #pragma unroll
            for (int nt = 0; nt < 4; ++nt)
                bfv[nt] = *(const bf16x8*)(sBc + (rowB0 + nt * 16) * 128 + ((so ^ sw) * 16));
            #pragma unroll
            for (int mt = 0; mt < 4; ++mt)
                #pragma unroll
                for (int nt = 0; nt < 4; ++nt)
                    acc[mt][nt] = __builtin_amdgcn_mfma_f32_16x16x32_bf16(af[mt], bfv[nt], acc[mt][nt], 0, 0, 0);
        }
        __syncthreads();
    }

    float bv[4];
    #pragma unroll
    for (int nt = 0; nt < 4; ++nt) bv[nt] = bias[bn * 128 + wn * 64 + nt * 16 + c];
    #pragma unroll
    for (int mt = 0; mt < 4; ++mt)
        #pragma unroll
        for (int r = 0; r < 4; ++r) {
            int row = bm * 128 + wm * 64 + mt * 16 + quad * 4 + r;
            float* cp = C + (size_t)row * N + bn * 128 + wn * 64 + c;
            #pragma unroll
            for (int nt = 0; nt < 4; ++nt) cp[nt * 16] = acc[mt][nt][r] + bv[nt];
        }
}

// ---------------- fixup: L2-normalize XQ/XK, XV <- ln(xv-xk)+xk ----------------
__global__ __launch_bounds__(256) void fixup_kernel(float* __restrict__ XQ, float* __restrict__ XK,
                                                    float* __restrict__ XV,
                                                    const float* __restrict__ lnw_g,
                                                    const float* __restrict__ lnb_g) {
    int g = blockIdx.x * 4 + (threadIdx.x >> 6); // (b*L+l)*H + h
    int d = threadIdx.x & 63;
    int h = g & (Hh - 1);
    size_t base = (size_t)(g >> 5) * Dd + h * 64 + d;
    float q = XQ[base], k = XK[base], v = XV[base];
    float nq = sqrtf(wsum64(q * q)); q /= fmaxf(nq, 1e-12f);
    float nk = sqrtf(wsum64(k * k)); k /= fmaxf(nk, 1e-12f);
    float diff = v - k;
    float mu = wsum64(diff) * (1.f / 64.f);
    float cc = diff - mu;
    float var = wsum64(cc * cc) * (1.f / 63.f); // ddof=1
    float vn = lnw_g[h * 64 + d] * cc / (sqrtf(var) + 1e-8f) + lnb_g[h * 64 + d] + k;
    XQ[base] = q; XK[base] = k; XV[base] = vn;
}

// ---------------- lr: s[b,h,l] = sigmoid(hs[b,l,:]·lr_w[h,:] + lr_b[h]) / (HD*K) ----------------
__global__ __launch_bounds__(256) void lr_kernel(const float* __restrict__ hs,
                                                 const float* __restrict__ lrw,
                                                 const float* __restrict__ lrb,
                                                 float* __restrict__ lr_out) {
    int tok = blockIdx.x; // b*L + l
    int t = threadIdx.x;
    int h = t >> 3, j0 = t & 7;
    const float* row = hs + (size_t)tok * Dd;
    const float* wr = lrw + (size_t)h * Dd;
    float p = 0.f;
    for (int j = j0 * 4; j < Dd; j += 32) {
        float4 a = *(const float4*)(row + j);
        float4 w = *(const float4*)(wr + j);
        p += a.x * w.x + a.y * w.y + a.z * w.z + a.w * w.w;
    }
    __shared__ float red[32][8];
    red[h][j0] = p;
    __syncthreads();
    if (t < 32) {
        float s = 0.f;
        #pragma unroll
        for (int i = 0; i < 8; ++i) s += red[t][i];
        s += lrb[t];
        s = 1.f / (1.f + expf(-s));
        s *= 1.0f / (HD * MBK);
        int b = tok >> 12, l = tok & (Ls - 1);
        lr_out[(size_t)(b * Hh + t) * Ls + l] = s;
    }
}

// ---------------- MFMA TTT scan: 4 waves per (b,h) chain ----------------
// Wave w owns output-column slab S_w = [16w, 16w+16). All operands LDS-resident.
// mfma_f32_16x16x32_bf16 layouts:
//   A-frag lane(q,n): A[m=n][k=8q+j]   B-frag: B[k=8q+j][n]   C: C[4q+r][n]
// W1 resident as bf16 hi+lo, transposed wt[col][k] (direct b128 B-frag reads).
// grad/sxk/att stored K=32 zero-padded -> unmasked K=32 frags for small MFMAs.
// Reductions are DPP-based (no LDS); 3 barriers/step:
//   B1 after MFMA phase (zT z1-bounce + att32), B2 after grad phase
//   (gbufT/sxkT/pb), B3 after W1 update (zbT zbar-bounce).
//   Old B4 removed: zbar uses its own zbT buffer, and all cross-step tile/
//   svb/att32/zT hazards are already ordered by B2/B3 + next step's B1.
__global__ __launch_bounds__(256, 1) void scan_kernel(const float* __restrict__ XQ,
                                                      const float* __restrict__ XK,
                                                      const float* __restrict__ XV,
                                                      const float* __restrict__ lrbuf,
                                                      const float* __restrict__ W1in,
                                                      const float* __restrict__ b1in,
                                                      const float* __restrict__ lnw_g,
                                                      const float* __restrict__ lnb_g,
                                                      float* __restrict__ Y) {
    int bh = blockIdx.x;          // b*H + h
    int b = bh >> 5, h = bh & 31;
    int t = threadIdx.x;
    int w = t >> 6;               // wave 0..3
    int lane = t & 63;
    int q = lane >> 4, n = lane & 15;
    int gc = 16 * w + n;          // this lane's C-layout global column

    __shared__ float tiles[2][3][16 * 68];     // [buf][xq,xk,xv][token][feat]
    __shared__ float svb[2][16];
    __shared__ unsigned short wt_hi[64 * 72];  // [col][k]
    __shared__ unsigned short wt_lo[64 * 72];
    __shared__ float zT[64 * 20];              // [col][token] z1 bounce
    __shared__ float zbT[64 * 20];             // [col][token] zbar bounce
    __shared__ unsigned short gbufT[64 * 32];  // [col][k] bf16, k>=16 zero
    __shared__ unsigned short sxkT[64 * 32];   // [col][k] bf16, k>=16 zero
    __shared__ float att32[16 * 32];           // [i][j] fp32, j>=16 zero
    __shared__ float pb[4 * 64];               // b1-partials [wave][col]

    // ---- init W1 as hi/lo bf16, transposed ----
    #pragma unroll
    for (int i = 0; i < 16; ++i) {
        int k = i * 4 + w;        // 0..63
        float val = W1in[(size_t)h * 4096 + (size_t)k * 64 + lane];
        unsigned short hi = f2bf(val);
        unsigned short lo = f2bf(val - b2f(hi));
        wt_hi[lane * 72 + k] = hi;
        wt_lo[lane * 72 + k] = lo;
    }
    // ---- zero pads ----
    #pragma unroll
    for (int i = 0; i < 8; ++i) { gbufT[i * 256 + t] = 0; sxkT[i * 256 + t] = 0; }
    #pragma unroll
    for (int i = 0; i < 2; ++i) att32[i * 256 + t] = 0.f;

    float b1r = b1in[h * 64 + lane];
    float lnwr = lnw_g[h * 64 + lane];
    float lnbr = lnb_g[h * 64 + lane];

    const size_t gbase = ((size_t)b * Ls) * Dd + h * 64;
    const float* lrp = lrbuf + (size_t)bh * Ls;

    int rowp = t >> 4, c4p = (t & 15) * 4;     // staging pattern: 16 rows x 16 float4
    // ---- prologue: step 0 direct to LDS, prefetch step 1 ----
    *(float4*)&tiles[0][0][rowp * 68 + c4p] = *(const float4*)(XQ + gbase + (size_t)rowp * Dd + c4p);
    *(float4*)&tiles[0][1][rowp * 68 + c4p] = *(const float4*)(XK + gbase + (size_t)rowp * Dd + c4p);
    *(float4*)&tiles[0][2][rowp * 68 + c4p] = *(const float4*)(XV + gbase + (size_t)rowp * Dd + c4p);
    if (t < 16) svb[0][t] = lrp[t];
    float4 preq = *(const float4*)(XQ + gbase + (size_t)(16 + rowp) * Dd + c4p);
    float4 prek = *(const float4*)(XK + gbase + (size_t)(16 + rowp) * Dd + c4p);
    float4 prev = *(const float4*)(XV + gbase + (size_t)(16 + rowp) * Dd + c4p);
    float presv = (t < 16) ? lrp[16 + t] : 0.f;
    __syncthreads();

    const f32x4 zero4 = {0.f, 0.f, 0.f, 0.f};

    for (int nmb = 0; nmb < NMBc; ++nmb) {
        int cb = nmb & 1, nb2 = cb ^ 1;
        int l0 = nmb * 16;
        // ---- stage step n+1 (from prefetch regs), issue prefetch n+2 ----
        *(float4*)&tiles[nb2][0][rowp * 68 + c4p] = preq;
        *(float4*)&tiles[nb2][1][rowp * 68 + c4p] = prek;
        *(float4*)&tiles[nb2][2][rowp * 68 + c4p] = prev;
        if (t < 16) svb[nb2][t] = presv;
        int lp = (l0 + 32 <= Ls - 16) ? (l0 + 32) : (Ls - 16);
        preq = *(const float4*)(XQ + gbase + (size_t)(lp + rowp) * Dd + c4p);
        prek = *(const float4*)(XK + gbase + (size_t)(lp + rowp) * Dd + c4p);
        prev = *(const float4*)(XV + gbase + (size_t)(lp + rowp) * Dd + c4p);
        presv = (t < 16) ? lrp[lp + t] : 0.f;

        const float* xqs = &tiles[cb][0][0];
        const float* xks = &tiles[cb][1][0];
        const float* xvs = &tiles[cb][2][0];

        // ---- build xq/xk A-frags (token n, feats 8q+j / 32+8q+j) ----
        bf16x8 qf0, qf1, kf0, kf1;
        {
            float4 a0 = *(const float4*)&xqs[n * 68 + 8 * q];
            float4 a1 = *(const float4*)&xqs[n * 68 + 8 * q + 4];
            float4 a2 = *(const float4*)&xqs[n * 68 + 32 + 8 * q];
            float4 a3 = *(const float4*)&xqs[n * 68 + 32 + 8 * q + 4];
            qf0[0]=(__bf16)a0.x; qf0[1]=(__bf16)a0.y; qf0[2]=(__bf16)a0.z; qf0[3]=(__bf16)a0.w;
            qf0[4]=(__bf16)a1.x; qf0[5]=(__bf16)a1.y; qf0[6]=(__bf16)a1.z; qf0[7]=(__bf16)a1.w;
            qf1[0]=(__bf16)a2.x; qf1[1]=(__bf16)a2.y; qf1[2]=(__bf16)a2.z; qf1[3]=(__bf16)a2.w;
            qf1[4]=(__bf16)a3.x; qf1[5]=(__bf16)a3.y; qf1[6]=(__bf16)a3.z; qf1[7]=(__bf16)a3.w;
            float4 k0 = *(const float4*)&xks[n * 68 + 8 * q];
            float4 k1 = *(const float4*)&xks[n * 68 + 8 * q + 4];
            float4 k2 = *(const float4*)&xks[n * 68 + 32 + 8 * q];
            float4 k3 = *(const float4*)&xks[n * 68 + 32 + 8 * q + 4];
            kf0[0]=(__bf16)k0.x; kf0[1]=(__bf16)k0.y; kf0[2]=(__bf16)k0.z; kf0[3]=(__bf16)k0.w;
            kf0[4]=(__bf16)k1.x; kf0[5]=(__bf16)k1.y; kf0[6]=(__bf16)k1.z; kf0[7]=(__bf16)k1.w;
            kf1[0]=(__bf16)k2.x; kf1[1]=(__bf16)k2.y; kf1[2]=(__bf16)k2.z; kf1[3]=(__bf16)k2.w;
            kf1[4]=(__bf16)k3.x; kf1[5]=(__bf16)k3.y; kf1[6]=(__bf16)k3.z; kf1[7]=(__bf16)k3.w;
        }
        // ---- W1 B-frags (own slab) ----
        bf16x8 wh0 = *(const bf16x8*)&wt_hi[gc * 72 + 8 * q];
        bf16x8 wh1 = *(const bf16x8*)&wt_hi[gc * 72 + 32 + 8 * q];
        bf16x8 wl0 = *(const bf16x8*)&wt_lo[gc * 72 + 8 * q];
        bf16x8 wl1 = *(const bf16x8*)&wt_lo[gc * 72 + 32 + 8 * q];

        // ---- MFMAs: Attn (redundant per wave), Z1 slab, Zbar partial ----
        f32x4 aacc = __builtin_amdgcn_mfma_f32_16x16x32_bf16(qf1, kf1, zero4, 0, 0, 0);
        aacc = __builtin_amdgcn_mfma_f32_16x16x32_bf16(qf0, kf0, aacc, 0, 0, 0);
        f32x4 z1 = __builtin_amdgcn_mfma_f32_16x16x32_bf16(kf0, wh0, zero4, 0, 0, 0);
        z1 = __builtin_amdgcn_mfma_f32_16x16x32_bf16(kf1, wh1, z1, 0, 0, 0);
        z1 = __builtin_amdgcn_mfma_f32_16x16x32_bf16(kf0, wl0, z1, 0, 0, 0);
        z1 = __builtin_amdgcn_mfma_f32_16x16x32_bf16(kf1, wl1, z1, 0, 0, 0);
        f32x4 zb = __builtin_amdgcn_mfma_f32_16x16x32_bf16(qf0, wh0, zero4, 0, 0, 0);
        zb = __builtin_amdgcn_mfma_f32_16x16x32_bf16(qf1, wh1, zb, 0, 0, 0);
        zb = __builtin_amdgcn_mfma_f32_16x16x32_bf16(qf0, wl0, zb, 0, 0, 0);
        zb = __builtin_amdgcn_mfma_f32_16x16x32_bf16(qf1, wl1, zb, 0, 0, 0);

        // ---- bounce Z1 (transposed) ----
        {
            float4 zs; zs.x = z1[0]; zs.y = z1[1]; zs.z = z1[2]; zs.w = z1[3];
            *(float4*)&zT[gc * 20 + 4 * q] = zs;
        }
        // ---- masked -sv_j*(Attn+1) (wave 0 writes) ----
        if (w == 0) {
            float svn = svb[cb][n];
            #pragma unroll
            for (int r = 0; r < 4; ++r) {
                int i = 4 * q + r;
                att32[i * 32 + n] = (i >= n) ? (-svn * (aacc[r] + 1.f)) : 0.f;
            }
        }
        __syncthreads(); // B1

        // ======== row-major grad phase: lane = col, rows 4w+r ========
        float4 zz = *(const float4*)&zT[lane * 20 + 4 * w];
        float zar[4] = {zz.x + b1r, zz.y + b1r, zz.z + b1r, zz.w + b1r};
        float xk_rm[4], xv_rm[4], xq_rm[4];
        #pragma unroll
        for (int r = 0; r < 4; ++r) {
            int rw = 4 * w + r;
            xk_rm[r] = xks[rw * 68 + lane];
            xv_rm[r] = xvs[rw * 68 + lane];
            xq_rm[r] = xqs[rw * 68 + lane];
        }
        float4 svr4 = *(const float4*)&svb[cb][4 * w];
        float svr[4] = {svr4.x, svr4.y, svr4.z, svr4.w};
        float gr[4]; float pbv = 0.f;
        #pragma unroll
        for (int r = 0; r < 4; ++r) {
            float s1 = wsum64(zar[r]);
            float s2 = wsum64(zar[r] * zar[r]);
            float mu = s1 * (1.f / 64.f);
            float var = s2 * (1.f / 64.f) - mu * mu;
            float rstd = rsqrtf(var + 1e-6f);
            float xh = (zar[r] - mu) * rstd;
            float g = (lnwr * xh + lnbr - (xv_rm[r] - xk_rm[r])) * lnwr;
            float sg = wsum64(g);
            float sxg = wsum64(xh * g);
            gr[r] = (64.f * g - sg - xh * sxg) * rstd * (1.f / 64.f);
            pbv += svr[r] * gr[r];
        }
        {
            ushort4 gp, sp;
            gp.x = f2bf(gr[0]); gp.y = f2bf(gr[1]); gp.z = f2bf(gr[2]); gp.w = f2bf(gr[3]);
            sp.x = f2bf(svr[0] * xk_rm[0]); sp.y = f2bf(svr[1] * xk_rm[1]);
            sp.z = f2bf(svr[2] * xk_rm[2]); sp.w = f2bf(svr[3] * xk_rm[3]);
            *(ushort4*)&gbufT[lane * 32 + 4 * w] = gp;
            *(ushort4*)&sxkT[lane * 32 + 4 * w] = sp;
            pb[w * 64 + lane] = pbv;
        }
        __syncthreads(); // B2

        // ---- grad B-frag (own slab), masked-attn A-frag (K=32, zero-padded) ----
        bf16x8 gF = *(const bf16x8*)&gbufT[gc * 32 + 8 * q];
        bf16x8 amF;
        {
            float4 f0 = *(const float4*)&att32[n * 32 + 8 * q];
            float4 f1 = *(const float4*)&att32[n * 32 + 8 * q + 4];
            amF[0]=(__bf16)f0.x; amF[1]=(__bf16)f0.y; amF[2]=(__bf16)f0.z; amF[3]=(__bf16)f0.w;
            amF[4]=(__bf16)f1.x; amF[5]=(__bf16)f1.y; amF[6]=(__bf16)f1.z; amF[7]=(__bf16)f1.w;
        }
        // ---- finish Zbar, bounce transposed (own buffer, B4 no longer needed) ----
        zb = __builtin_amdgcn_mfma_f32_16x16x32_bf16(amF, gF, zb, 0, 0, 0);
        {
            float4 zs; zs.x = zb[0]; zs.y = zb[1]; zs.z = zb[2]; zs.w = zb[3];
            *(float4*)&zbT[gc * 20 + 4 * q] = zs;
        }
        // ---- W1 update: own slab -= (sv.xk)^T @ grad ----
        #pragma unroll
        for (int tm = 0; tm < 4; ++tm) {
            bf16x8 ax = *(const bf16x8*)&sxkT[(16 * tm + n) * 32 + 8 * q];
            f32x4 dl = __builtin_amdgcn_mfma_f32_16x16x32_bf16(ax, gF, zero4, 0, 0, 0);
            int ko = 16 * tm + 4 * q;
            ushort4 h4 = *(ushort4*)&wt_hi[gc * 72 + ko];
            ushort4 l4 = *(ushort4*)&wt_lo[gc * 72 + ko];
            float w0 = b2f(h4.x) + b2f(l4.x) - dl[0];
            float w1 = b2f(h4.y) + b2f(l4.y) - dl[1];
            float w2 = b2f(h4.z) + b2f(l4.z) - dl[2];
            float w3 = b2f(h4.w) + b2f(l4.w) - dl[3];
            h4.x = f2bf(w0); l4.x = f2bf(w0 - b2f(h4.x));
            h4.y = f2bf(w1); l4.y = f2bf(w1 - b2f(h4.y));
            h4.z = f2bf(w2); l4.z = f2bf(w2 - b2f(h4.z));
            h4.w = f2bf(w3); l4.w = f2bf(w3 - b2f(h4.w));
            *(ushort4*)&wt_hi[gc * 72 + ko] = h4;
            *(ushort4*)&wt_lo[gc * 72 + ko] = l4;
        }
        // ---- b1 update (uses old b1r after B3) ----
        float b1n_ = b1r - (pb[0 * 64 + lane] + pb[1 * 64 + lane] +
                            pb[2 * 64 + lane] + pb[3 * 64 + lane]);
        __syncthreads(); // B3

        // ======== row-major Zbar LN + output ========
        float4 zz2 = *(const float4*)&zbT[lane * 20 + 4 * w];
        float zbr[4] = {zz2.x + b1r, zz2.y + b1r, zz2.z + b1r, zz2.w + b1r};
        #pragma unroll
        for (int r = 0; r < 4; ++r) {
            float s1 = wsum64(zbr[r]);
            float s2 = wsum64(zbr[r] * zbr[r]);
            float mu = s1 * (1.f / 64.f);
            float var = s2 * (1.f / 64.f) - mu * mu;
            float rstd = rsqrtf(var + 1e-6f);
            float o = lnwr * ((zbr[r] - mu) * rstd) + lnbr + xq_rm[r];
            Y[gbase + (size_t)(l0 + 4 * w + r) * Dd + lane] = o;
        }
        b1r = b1n_;
        // no B4: zbar uses zbT; all cross-step LDS hazards are ordered by
        // B2/B3 of this step + B1 of the next step.
    }
}

// ---------------- post layernorm over D + cast to bf16 ----------------
__global__ __launch_bounds__(256) void postnorm_kernel(const float* __restrict__ Y,
                                                       const float* __restrict__ pw,
                                                       const float* __restrict__ pb,
                                                       unsigned short* __restrict__ Yb) {
    int tok = blockIdx.x, t = threadIdx.x;
    const float* row = Y + (size_t)tok * Dd;
    int c0 = t * 4, c1 = 1024 + t * 4;
    float4 v0 = *(const float4*)(row + c0);
    float4 v1 = *(const float4*)(row + c1);
    float s1 = v0.x + v0.y + v0.z + v0.w + v1.x + v1.y + v1.z + v1.w;
    float s2 = v0.x * v0.x + v0.y * v0.y + v0.z * v0.z + v0.w * v0.w +
               v1.x * v1.x + v1.y * v1.y + v1.z * v1.z + v1.w * v1.w;
    s1 = wsum64(s1); s2 = wsum64(s2);
    __shared__ float r1[4], r2[4];
    if ((t & 63) == 0) { r1[t >> 6] = s1; r2[t >> 6] = s2; }
    __syncthreads();
    float S1 = r1[0] + r1[1] + r1[2] + r1[3];
    float S2 = r2[0] + r2[1] + r2[2] + r2[3];
    float mu = S1 * (1.f / 2048.f);
    float var = S2 * (1.f / 2048.f) - mu * mu;
    float rstd = rsqrtf(var + 1e-6f);
    float4 w0 = *(const float4*)(pw + c0), b0 = *(const float4*)(pb + c0);
    float4 w1 = *(const float4*)(pw + c1), b1 = *(const float4*)(pb + c1);
    ushort4 o0, o1;
    o0.x = f2bf((v0.x - mu) * rstd * w0.x + b0.x);
    o0.y = f2bf((v0.y - mu) * rstd * w0.y + b0.y);
    o0.z = f2bf((v0.z - mu) * rstd * w0.z + b0.z);
    o0.w = f2bf((v0.w - mu) * rstd * w0.w + b0.w);
    o1.x = f2bf((v1.x - mu) * rstd * w1.x + b1.x);
    o1.y = f2bf((v1.y - mu) * rstd * w1.y + b1.y);
    o1.z = f2bf((v1.z - mu) * rstd * w1.z + b1.z);
    o1.w = f2bf((v1.w - mu) * rstd * w1.w + b1.w);
    *(ushort4*)(Yb + (size_t)tok * Dd + c0) = o0;
    *(ushort4*)(Yb + (size_t)tok * Dd + c1) = o1;
}

extern "C" void kernel_launch(void* const* d_in, const int* in_sizes, int n_in,
                              void* d_out, int out_size, void* d_ws, size_t ws_size,
                              hipStream_t stream) {
    const float* hs   = (const float*)d_in[0];
    const float* wq_w = (const float*)d_in[1];
    const float* wq_b = (const float*)d_in[2];
    const float* wk_w = (const float*)d_in[3];
    const float* wk_b = (const float*)d_in[4];
    const float* wv_w = (const float*)d_in[5];
    const float* wv_b = (const float*)d_in[6];
    const float* wo_w = (const float*)d_in[7];
    const float* wo_b = (const float*)d_in[8];
    const float* lnw  = (const float*)d_in[9];
    const float* lnb  = (const float*)d_in[10];
    const float* lr_w = (const float*)d_in[11];
    const float* lr_b = (const float*)d_in[12];
    const float* W1   = (const float*)d_in[13];
    const float* b1   = (const float*)d_in[14];
    const float* pnw  = (const float*)d_in[15];
    const float* pnb  = (const float*)d_in[16];
    float* out = (float*)d_out;

    char* ws = (char*)d_ws;
    size_t off = 0;
    auto alloc = [&](size_t bytes) -> void* {
        void* p = ws + off; off += (bytes + 255) & ~(size_t)255; return p;
    };
    unsigned short* hsb = (unsigned short*)alloc((size_t)MTOK * Dd * 2);
    unsigned short* wtb = (unsigned short*)alloc((size_t)Dd * Dd * 2);
    float* XQ = (float*)alloc((size_t)MTOK * Dd * 4);
    float* XK = (float*)alloc((size_t)MTOK * Dd * 4);
    float* XV = (float*)alloc((size_t)MTOK * Dd * 4);
    float* lrbuf = (float*)alloc((size_t)Bb * Hh * Ls * 4);
    float* Y = XQ;                 // safe alias (per-chain row/col ownership; writes trail reads)
    unsigned short* Yb = hsb;      // hsb dead after QKV GEMMs

    dim3 blk(256);
    cast_hs_kernel<<<dim3(MTOK * Dd / 1024), blk, 0, stream>>>(hs, hsb);

    transpose_cast_kernel<<<dim3(1024), blk, 0, stream>>>(wq_w, wtb);
    gemm_bt_kernel<<<dim3(64, 16), blk, 0, stream>>>(hsb, wtb, wq_b, XQ, MTOK, Dd, Dd);
    transpose_cast_kernel<<<dim3(1024), blk, 0, stream>>>(wk_w, wtb);
    gemm_bt_kernel<<<dim3(64, 16), blk, 0, stream>>>(hsb, wtb, wk_b, XK, MTOK, Dd, Dd);
    transpose_cast_kernel<<<dim3(1024), blk, 0, stream>>>(wv_w, wtb);
    gemm_bt_kernel<<<dim3(64, 16), blk, 0, stream>>>(hsb, wtb, wv_b, XV, MTOK, Dd, Dd);

    fixup_kernel<<<dim3(Bb * Ls * Hh / 4), blk, 0, stream>>>(XQ, XK, XV, lnw, lnb);
    lr_kernel<<<dim3(MTOK), blk, 0, stream>>>(hs, lr_w, lr_b, lrbuf);

    scan_kernel<<<dim3(Bb * Hh), blk, 0, stream>>>(XQ, XK, XV, lrbuf, W1, b1, lnw, lnb, Y);

    postnorm_kernel<<<dim3(MTOK), blk, 0, stream>>>(Y, pnw, pnb, Yb);

    transpose_cast_kernel<<<dim3(1024), blk, 0, stream>>>(wo_w, wtb);
    gemm_bt_kernel<<<dim3(64, 16), blk, 0, stream>>>(Yb, wtb, wo_b, out, MTOK, Dd, Dd);
}

// Round 3
// 1413.166 us; speedup vs baseline: 1.2423x; 1.1082x over previous
//
#include <hip/hip_runtime.h>
#include <hip/hip_bf16.h>
#include <cstdint>
#include <cstddef>

#define DEV __device__ __forceinline__

constexpr int Bb = 2, Ls = 4096, Dd = 2048, Hh = 32, HD = 64, MBK = 16, NMBc = 256;
constexpr int MTOK = Bb * Ls; // 8192 tokens

typedef __bf16 bf16x8 __attribute__((ext_vector_type(8)));
typedef float  f32x4  __attribute__((ext_vector_type(4)));

// hardware RNE f32->bf16 (v_cvt_pk_bf16_f32); replaces 5-op software round
DEV unsigned short f2bf(float f) {
    union { __bf16 h; unsigned short u; } x;
    x.h = (__bf16)f;
    return x.u;
}
DEV float b2f(unsigned short u) {
    union { unsigned int i; float f; } x; x.i = ((unsigned int)u) << 16;
    return x.f;
}

// 64-lane sum via DPP; lane 63 holds total, readlane broadcasts (uniform use).
DEV float wsum64(float v) {
    int t;
    t = __builtin_amdgcn_update_dpp(0, __float_as_int(v), 0x111, 0xf, 0xf, true); v += __int_as_float(t);
    t = __builtin_amdgcn_update_dpp(0, __float_as_int(v), 0x112, 0xf, 0xf, true); v += __int_as_float(t);
    t = __builtin_amdgcn_update_dpp(0, __float_as_int(v), 0x114, 0xf, 0xf, true); v += __int_as_float(t);
    t = __builtin_amdgcn_update_dpp(0, __float_as_int(v), 0x118, 0xf, 0xf, true); v += __int_as_float(t);
    t = __builtin_amdgcn_update_dpp(0, __float_as_int(v), 0x142, 0xa, 0xf, true); v += __int_as_float(t);
    t = __builtin_amdgcn_update_dpp(0, __float_as_int(v), 0x143, 0xc, 0xf, true); v += __int_as_float(t);
    return __int_as_float(__builtin_amdgcn_readlane(__float_as_int(v), 63));
}

// 16-lane (DPP row) rotate-reduce sum: every lane of each row-of-16 gets the row total.
DEV float rsum16(float v) {
    int t;
    t = __builtin_amdgcn_update_dpp(0, __float_as_int(v), 0x121, 0xf, 0xf, true); v += __int_as_float(t); // ror1
    t = __builtin_amdgcn_update_dpp(0, __float_as_int(v), 0x122, 0xf, 0xf, true); v += __int_as_float(t); // ror2
    t = __builtin_amdgcn_update_dpp(0, __float_as_int(v), 0x124, 0xf, 0xf, true); v += __int_as_float(t); // ror4
    t = __builtin_amdgcn_update_dpp(0, __float_as_int(v), 0x128, 0xf, 0xf, true); v += __int_as_float(t); // ror8
    return v;
}

DEV void g2l16(const void* g, void* l) {
    __builtin_amdgcn_global_load_lds(
        (__attribute__((address_space(1))) void*)(g),
        (__attribute__((address_space(3))) void*)(l), 16, 0, 0);
}

// ---------------- cast hidden_states fp32 -> bf16 ----------------
__global__ __launch_bounds__(256) void cast_hs_kernel(const float* __restrict__ src,
                                                      unsigned short* __restrict__ dst) {
    int i = (blockIdx.x * 256 + threadIdx.x) * 4;
    float4 v = *(const float4*)(src + i);
    ushort4 o; o.x = f2bf(v.x); o.y = f2bf(v.y); o.z = f2bf(v.z); o.w = f2bf(v.w);
    *(ushort4*)(dst + i) = o;
}

// ---------------- transpose + cast weight: W[k][n] fp32 -> Wt[n][k] bf16 ----------------
__global__ __launch_bounds__(256) void transpose_cast_kernel(const float* __restrict__ W,
                                                             unsigned short* __restrict__ Wt) {
    __shared__ float tile[64][65];
    int bx = blockIdx.x & 31;   // k-tile
    int by = blockIdx.x >> 5;   // n-tile
    int t = threadIdx.x;
    int r = t >> 4, c4 = (t & 15) * 4;
    #pragma unroll
    for (int i = 0; i < 4; ++i) {
        int row = r + i * 16;
        float4 v = *(const float4*)(W + (size_t)(bx * 64 + row) * Dd + by * 64 + c4);
        tile[row][c4 + 0] = v.x; tile[row][c4 + 1] = v.y;
        tile[row][c4 + 2] = v.z; tile[row][c4 + 3] = v.w;
    }
    __syncthreads();
    #pragma unroll
    for (int i = 0; i < 4; ++i) {
        int row = r + i * 16; // n index
        ushort4 o;
        o.x = f2bf(tile[c4 + 0][row]); o.y = f2bf(tile[c4 + 1][row]);
        o.z = f2bf(tile[c4 + 2][row]); o.w = f2bf(tile[c4 + 3][row]);
        *(ushort4*)(Wt + (size_t)(by * 64 + row) * Dd + bx * 64 + c4) = o;
    }
}

// ---------------- bf16 MFMA GEMM:  C[M,N] = A[M,K] @ Bt[N,K]^T + bias ----------------
__global__ __launch_bounds__(256) void gemm_bt_kernel(const unsigned short* __restrict__ A,
                                                      const unsigned short* __restrict__ Bt,
                                                      const float* __restrict__ bias,
                                                      float* __restrict__ C,
                                                      int M, int N, int Kd) {
    __shared__ unsigned short sA[128 * 64];
    __shared__ unsigned short sB[128 * 64];
    int t = threadIdx.x;
    int lane = t & 63;
    int wid = t >> 6, wm = wid >> 1, wn = wid & 1;
    int quad = lane >> 4, c = lane & 15;
    int bm = blockIdx.x, bn = blockIdx.y;

    const unsigned short* pa[4]; const unsigned short* pb[4];
    unsigned short* la[4]; unsigned short* lb[4];
    #pragma unroll
    for (int i = 0; i < 4; ++i) {
        int lin = i * 256 + t;
        int row = lin >> 3, blk = lin & 7;
        int oct = blk ^ (row & 7);
        pa[i] = A  + (size_t)(bm * 128 + row) * Kd + oct * 8;
        pb[i] = Bt + (size_t)(bn * 128 + row) * Kd + oct * 8;
        la[i] = sA + lin * 8;
        lb[i] = sB + lin * 8;
    }

    f32x4 acc[4][4];
    #pragma unroll
    for (int i = 0; i < 4; ++i)
        #pragma unroll
        for (int j = 0; j < 4; ++j)
            #pragma unroll
            for (int r = 0; r < 4; ++r) acc[i][j][r] = 0.f;

    const char* sAc = (const char*)sA;
    const char* sBc = (const char*)sB;
    int rowA0 = wm * 64 + c, rowB0 = wn * 64 + c;
    int sw = (c & 7);

    int nkt = Kd >> 6;
    for (int kt = 0; kt < nkt; ++kt) {
        #pragma unroll
        for (int i = 0; i < 4; ++i) {
            g2l16(pa[i], la[i]);
            g2l16(pb[i], lb[i]);
            pa[i] += 64; pb[i] += 64;
        }
        __syncthreads();
        #pragma unroll
        for (int s = 0; s < 2; ++s) {
            bf16x8 af[4], bfv[4];
            int so = (s << 2) | quad;
            #pragma unroll
            for (int mt = 0; mt < 4; ++mt)
                af[mt] = *(const bf16x8*)(sAc + (rowA0 + mt * 16) * 128 + ((so ^ sw) * 16));
            #pragma unroll
            for (int nt = 0; nt < 4; ++nt)
                bfv[nt] = *(const bf16x8*)(sBc + (rowB0 + nt * 16) * 128 + ((so ^ sw) * 16));
            #pragma unroll
            for (int mt = 0; mt < 4; ++mt)
                #pragma unroll
                for (int nt = 0; nt < 4; ++nt)
                    acc[mt][nt] = __builtin_amdgcn_mfma_f32_16x16x32_bf16(af[mt], bfv[nt], acc[mt][nt], 0, 0, 0);
        }
        __syncthreads();
    }

    float bv[4];
    #pragma unroll
    for (int nt = 0; nt < 4; ++nt) bv[nt] = bias[bn * 128 + wn * 64 + nt * 16 + c];
    #pragma unroll
    for (int mt = 0; mt < 4; ++mt)
        #pragma unroll
        for (int r = 0; r < 4; ++r) {
            int row = bm * 128 + wm * 64 + mt * 16 + quad * 4 + r;
            float* cp = C + (size_t)row * N + bn * 128 + wn * 64 + c;
            #pragma unroll
            for (int nt = 0; nt < 4; ++nt) cp[nt * 16] = acc[mt][nt][r] + bv[nt];
        }
}

// ---------------- lr: s[b,h,l] = sigmoid(hs[b,l,:]·lr_w[h,:] + lr_b[h]) / (HD*K) ----------------
__global__ __launch_bounds__(256) void lr_kernel(const float* __restrict__ hs,
                                                 const float* __restrict__ lrw,
                                                 const float* __restrict__ lrb,
                                                 float* __restrict__ lr_out) {
    int tok = blockIdx.x; // b*L + l
    int t = threadIdx.x;
    int h = t >> 3, j0 = t & 7;
    const float* row = hs + (size_t)tok * Dd;
    const float* wr = lrw + (size_t)h * Dd;
    float p = 0.f;
    for (int j = j0 * 4; j < Dd; j += 32) {
        float4 a = *(const float4*)(row + j);
        float4 w = *(const float4*)(wr + j);
        p += a.x * w.x + a.y * w.y + a.z * w.z + a.w * w.w;
    }
    __shared__ float red[32][8];
    red[h][j0] = p;
    __syncthreads();
    if (t < 32) {
        float s = 0.f;
        #pragma unroll
        for (int i = 0; i < 8; ++i) s += red[t][i];
        s += lrb[t];
        s = 1.f / (1.f + expf(-s));
        s *= 1.0f / (HD * MBK);
        int b = tok >> 12, l = tok & (Ls - 1);
        lr_out[(size_t)(b * Hh + t) * Ls + l] = s;
    }
}

// staging-time fixup: L2-normalize q,k; v <- ln(v-k)+k. Row = 16 lanes x float4.
// rsum16 latency hides under staging slack (tile n+1 not read until next step).
DEV void stage_qkv(float4 q, float4 k, float4 v,
                   float* tq, float* tk, float* tv,
                   unsigned short* bq, unsigned short* bk,
                   int rowp, int c4p, float4 lnw4, float4 lnb4) {
    float rq = 1.f / fmaxf(sqrtf(rsum16(q.x*q.x + q.y*q.y + q.z*q.z + q.w*q.w)), 1e-12f);
    q.x *= rq; q.y *= rq; q.z *= rq; q.w *= rq;
    float rk = 1.f / fmaxf(sqrtf(rsum16(k.x*k.x + k.y*k.y + k.z*k.z + k.w*k.w)), 1e-12f);
    k.x *= rk; k.y *= rk; k.z *= rk; k.w *= rk;
    float4 df; df.x = v.x - k.x; df.y = v.y - k.y; df.z = v.z - k.z; df.w = v.w - k.w;
    float mu = rsum16(df.x + df.y + df.z + df.w) * (1.f / 64.f);
    float4 cc; cc.x = df.x - mu; cc.y = df.y - mu; cc.z = df.z - mu; cc.w = df.w - mu;
    float var = rsum16(cc.x*cc.x + cc.y*cc.y + cc.z*cc.z + cc.w*cc.w) * (1.f / 63.f); // ddof=1
    float rs = 1.f / (sqrtf(var) + 1e-8f);
    float4 vn;
    vn.x = lnw4.x * cc.x * rs + lnb4.x + k.x;
    vn.y = lnw4.y * cc.y * rs + lnb4.y + k.y;
    vn.z = lnw4.z * cc.z * rs + lnb4.z + k.z;
    vn.w = lnw4.w * cc.w * rs + lnb4.w + k.w;
    *(float4*)&tq[rowp * 68 + c4p] = q;
    *(float4*)&tk[rowp * 68 + c4p] = k;
    *(float4*)&tv[rowp * 68 + c4p] = vn;
    ushort4 qb, kb;
    qb.x = f2bf(q.x); qb.y = f2bf(q.y); qb.z = f2bf(q.z); qb.w = f2bf(q.w);
    kb.x = f2bf(k.x); kb.y = f2bf(k.y); kb.z = f2bf(k.z); kb.w = f2bf(k.w);
    *(ushort4*)&bq[rowp * 72 + c4p] = qb;
    *(ushort4*)&bk[rowp * 72 + c4p] = kb;
}

// ---------------- MFMA TTT scan: 4 waves per (b,h) chain ----------------
// Wave w owns output-column slab S_w = [16w, 16w+16). All operands LDS-resident.
// mfma_f32_16x16x32_bf16 layouts:
//   A-frag lane(q,n): A[m=n][k=8q+j]   B-frag: B[k=8q+j][n]   C: C[4q+r][n]
// W1 resident as bf16 hi+lo, transposed wt[col][k] (direct b128 B-frag reads).
// XQ/XK additionally kept as bf16 tiles (stride 72, bank-uniform) for direct
// b128 A-frag reads (no per-step cvt/pack). Fixup (L2 norm, LN) fused into
// staging via 16-lane DPP rotate-reduce. att stored bf16. z1/zb hi+lo MFMA
// chains split (depth 2) then added. 3 barriers/step.
__global__ __launch_bounds__(256, 1) void scan_kernel(const float* __restrict__ XQ,
                                                      const float* __restrict__ XK,
                                                      const float* __restrict__ XV,
                                                      const float* __restrict__ lrbuf,
                                                      const float* __restrict__ W1in,
                                                      const float* __restrict__ b1in,
                                                      const float* __restrict__ lnw_g,
                                                      const float* __restrict__ lnb_g,
                                                      float* __restrict__ Y) {
    int bh = blockIdx.x;          // b*H + h
    int b = bh >> 5, h = bh & 31;
    int t = threadIdx.x;
    int w = t >> 6;               // wave 0..3
    int lane = t & 63;
    int q = lane >> 4, n = lane & 15;
    int gc = 16 * w + n;          // this lane's C-layout global column

    __shared__ float tiles[2][3][16 * 68];     // [buf][xq,xk,xv][token][feat] fp32
    __shared__ unsigned short tbq[2][16 * 72]; // bf16 xq tiles (stride-72 pad)
    __shared__ unsigned short tbk[2][16 * 72]; // bf16 xk tiles
    __shared__ float svb[2][16];
    __shared__ unsigned short wt_hi[64 * 72];  // [col][k]
    __shared__ unsigned short wt_lo[64 * 72];
    __shared__ float zT[64 * 20];              // [col][token] z1 bounce
    __shared__ float zbT[64 * 20];             // [col][token] zbar bounce
    __shared__ unsigned short gbufT[64 * 32];  // [col][k] bf16, k>=16 zero
    __shared__ unsigned short sxkT[64 * 32];   // [col][k] bf16, k>=16 zero
    __shared__ unsigned short attb[16 * 32];   // [i][j] bf16, j>=16 zero
    __shared__ float pb[4 * 64];               // b1-partials [wave][col]

    // ---- init W1 as hi/lo bf16, transposed ----
    #pragma unroll
    for (int i = 0; i < 16; ++i) {
        int k = i * 4 + w;        // 0..63
        float val = W1in[(size_t)h * 4096 + (size_t)k * 64 + lane];
        unsigned short hi = f2bf(val);
        unsigned short lo = f2bf(val - b2f(hi));
        wt_hi[lane * 72 + k] = hi;
        wt_lo[lane * 72 + k] = lo;
    }
    // ---- zero pads ----
    #pragma unroll
    for (int i = 0; i < 8; ++i) { gbufT[i * 256 + t] = 0; sxkT[i * 256 + t] = 0; }
    #pragma unroll
    for (int i = 0; i < 2; ++i) attb[i * 256 + t] = 0;

    float b1r = b1in[h * 64 + lane];
    float lnwr = lnw_g[h * 64 + lane];
    float lnbr = lnb_g[h * 64 + lane];

    const size_t gbase = ((size_t)b * Ls) * Dd + h * 64;
    const float* lrp = lrbuf + (size_t)bh * Ls;

    int rowp = t >> 4, c4p = (t & 15) * 4;     // staging pattern: 16 rows x 16 float4
    float4 lnw4 = *(const float4*)(lnw_g + h * 64 + c4p);
    float4 lnb4 = *(const float4*)(lnb_g + h * 64 + c4p);

    // ---- prologue: step 0 staged (+fixup), prefetch step 1 (raw) ----
    {
        float4 q0 = *(const float4*)(XQ + gbase + (size_t)rowp * Dd + c4p);
        float4 k0 = *(const float4*)(XK + gbase + (size_t)rowp * Dd + c4p);
        float4 v0 = *(const float4*)(XV + gbase + (size_t)rowp * Dd + c4p);
        stage_qkv(q0, k0, v0, &tiles[0][0][0], &tiles[0][1][0], &tiles[0][2][0],
                  tbq[0], tbk[0], rowp, c4p, lnw4, lnb4);
    }
    if (t < 16) svb[0][t] = lrp[t];
    float4 preq = *(const float4*)(XQ + gbase + (size_t)(16 + rowp) * Dd + c4p);
    float4 prek = *(const float4*)(XK + gbase + (size_t)(16 + rowp) * Dd + c4p);
    float4 prev = *(const float4*)(XV + gbase + (size_t)(16 + rowp) * Dd + c4p);
    float presv = (t < 16) ? lrp[16 + t] : 0.f;
    __syncthreads();

    const f32x4 zero4 = {0.f, 0.f, 0.f, 0.f};

    for (int nmb = 0; nmb < NMBc; ++nmb) {
        int cb = nmb & 1, nb2 = cb ^ 1;
        int l0 = nmb * 16;
        // ---- stage step n+1 (+fused fixup), issue prefetch n+2 ----
        stage_qkv(preq, prek, prev, &tiles[nb2][0][0], &tiles[nb2][1][0], &tiles[nb2][2][0],
                  tbq[nb2], tbk[nb2], rowp, c4p, lnw4, lnb4);
        if (t < 16) svb[nb2][t] = presv;
        int lp = (l0 + 32 <= Ls - 16) ? (l0 + 32) : (Ls - 16);
        preq = *(const float4*)(XQ + gbase + (size_t)(lp + rowp) * Dd + c4p);
        prek = *(const float4*)(XK + gbase + (size_t)(lp + rowp) * Dd + c4p);
        prev = *(const float4*)(XV + gbase + (size_t)(lp + rowp) * Dd + c4p);
        presv = (t < 16) ? lrp[lp + t] : 0.f;

        const float* xqs = &tiles[cb][0][0];
        const float* xks = &tiles[cb][1][0];
        const float* xvs = &tiles[cb][2][0];
        const unsigned short* bqs = tbq[cb];
        const unsigned short* bks = tbk[cb];

        // ---- xq/xk A-frags: direct b128 reads from bf16 tiles ----
        bf16x8 qf0 = *(const bf16x8*)&bqs[n * 72 + 8 * q];
        bf16x8 qf1 = *(const bf16x8*)&bqs[n * 72 + 32 + 8 * q];
        bf16x8 kf0 = *(const bf16x8*)&bks[n * 72 + 8 * q];
        bf16x8 kf1 = *(const bf16x8*)&bks[n * 72 + 32 + 8 * q];

        // ---- W1 B-frags (own slab) ----
        bf16x8 wh0 = *(const bf16x8*)&wt_hi[gc * 72 + 8 * q];
        bf16x8 wh1 = *(const bf16x8*)&wt_hi[gc * 72 + 32 + 8 * q];
        bf16x8 wl0 = *(const bf16x8*)&wt_lo[gc * 72 + 8 * q];
        bf16x8 wl1 = *(const bf16x8*)&wt_lo[gc * 72 + 32 + 8 * q];

        // ---- MFMAs: Z1 slab, Zbar partial (hi/lo split, depth 2) ----
        f32x4 z1 = __builtin_amdgcn_mfma_f32_16x16x32_bf16(kf0, wh0, zero4, 0, 0, 0);
        z1 = __builtin_amdgcn_mfma_f32_16x16x32_bf16(kf1, wh1, z1, 0, 0, 0);
        f32x4 z1l = __builtin_amdgcn_mfma_f32_16x16x32_bf16(kf0, wl0, zero4, 0, 0, 0);
        z1l = __builtin_amdgcn_mfma_f32_16x16x32_bf16(kf1, wl1, z1l, 0, 0, 0);
        z1 = z1 + z1l;
        f32x4 zb = __builtin_amdgcn_mfma_f32_16x16x32_bf16(qf0, wh0, zero4, 0, 0, 0);
        zb = __builtin_amdgcn_mfma_f32_16x16x32_bf16(qf1, wh1, zb, 0, 0, 0);
        f32x4 zbl = __builtin_amdgcn_mfma_f32_16x16x32_bf16(qf0, wl0, zero4, 0, 0, 0);
        zbl = __builtin_amdgcn_mfma_f32_16x16x32_bf16(qf1, wl1, zbl, 0, 0, 0);
        zb = zb + zbl;

        // ---- bounce Z1 (transposed) ----
        {
            float4 zs; zs.x = z1[0]; zs.y = z1[1]; zs.z = z1[2]; zs.w = z1[3];
            *(float4*)&zT[gc * 20 + 4 * q] = zs;
        }
        // ---- attn + masked -sv_j*(Attn+1) as bf16 (wave 0 only) ----
        if (w == 0) {
            f32x4 aacc = __builtin_amdgcn_mfma_f32_16x16x32_bf16(qf1, kf1, zero4, 0, 0, 0);
            aacc = __builtin_amdgcn_mfma_f32_16x16x32_bf16(qf0, kf0, aacc, 0, 0, 0);
            float svn = svb[cb][n];
            #pragma unroll
            for (int r = 0; r < 4; ++r) {
                int i = 4 * q + r;
                attb[i * 32 + n] = f2bf((i >= n) ? (-svn * (aacc[r] + 1.f)) : 0.f);
            }
        }
        __syncthreads(); // B1

        // ======== row-major grad phase: lane = col, rows 4w+r ========
        float4 zz = *(const float4*)&zT[lane * 20 + 4 * w];
        float zar[4] = {zz.x + b1r, zz.y + b1r, zz.z + b1r, zz.w + b1r};
        float xk_rm[4], xv_rm[4], xq_rm[4];
        #pragma unroll
        for (int r = 0; r < 4; ++r) {
            int rw = 4 * w + r;
            xk_rm[r] = xks[rw * 68 + lane];
            xv_rm[r] = xvs[rw * 68 + lane];
            xq_rm[r] = xqs[rw * 68 + lane];
        }
        float4 svr4 = *(const float4*)&svb[cb][4 * w];
        float svr[4] = {svr4.x, svr4.y, svr4.z, svr4.w};
        float gr[4]; float pbv = 0.f;
        #pragma unroll
        for (int r = 0; r < 4; ++r) {
            float s1 = wsum64(zar[r]);
            float s2 = wsum64(zar[r] * zar[r]);
            float mu = s1 * (1.f / 64.f);
            float var = s2 * (1.f / 64.f) - mu * mu;
            float rstd = rsqrtf(var + 1e-6f);
            float xh = (zar[r] - mu) * rstd;
            float g = (lnwr * xh + lnbr - (xv_rm[r] - xk_rm[r])) * lnwr;
            float sg = wsum64(g);
            float sxg = wsum64(xh * g);
            gr[r] = (64.f * g - sg - xh * sxg) * rstd * (1.f / 64.f);
            pbv += svr[r] * gr[r];
        }
        {
            ushort4 gp, sp;
            gp.x = f2bf(gr[0]); gp.y = f2bf(gr[1]); gp.z = f2bf(gr[2]); gp.w = f2bf(gr[3]);
            sp.x = f2bf(svr[0] * xk_rm[0]); sp.y = f2bf(svr[1] * xk_rm[1]);
            sp.z = f2bf(svr[2] * xk_rm[2]); sp.w = f2bf(svr[3] * xk_rm[3]);
            *(ushort4*)&gbufT[lane * 32 + 4 * w] = gp;
            *(ushort4*)&sxkT[lane * 32 + 4 * w] = sp;
            pb[w * 64 + lane] = pbv;
        }
        __syncthreads(); // B2

        // ---- grad B-frag (own slab), masked-attn A-frag (bf16 direct) ----
        bf16x8 gF = *(const bf16x8*)&gbufT[gc * 32 + 8 * q];
        bf16x8 amF = *(const bf16x8*)&attb[n * 32 + 8 * q];
        // ---- finish Zbar, bounce transposed ----
        zb = __builtin_amdgcn_mfma_f32_16x16x32_bf16(amF, gF, zb, 0, 0, 0);
        {
            float4 zs; zs.x = zb[0]; zs.y = zb[1]; zs.z = zb[2]; zs.w = zb[3];
            *(float4*)&zbT[gc * 20 + 4 * q] = zs;
        }
        // ---- W1 update: own slab -= (sv.xk)^T @ grad ----
        #pragma unroll
        for (int tm = 0; tm < 4; ++tm) {
            bf16x8 ax = *(const bf16x8*)&sxkT[(16 * tm + n) * 32 + 8 * q];
            f32x4 dl = __builtin_amdgcn_mfma_f32_16x16x32_bf16(ax, gF, zero4, 0, 0, 0);
            int ko = 16 * tm + 4 * q;
            ushort4 h4 = *(ushort4*)&wt_hi[gc * 72 + ko];
            ushort4 l4 = *(ushort4*)&wt_lo[gc * 72 + ko];
            float w0 = b2f(h4.x) + b2f(l4.x) - dl[0];
            float w1 = b2f(h4.y) + b2f(l4.y) - dl[1];
            float w2 = b2f(h4.z) + b2f(l4.z) - dl[2];
            float w3 = b2f(h4.w) + b2f(l4.w) - dl[3];
            h4.x = f2bf(w0); l4.x = f2bf(w0 - b2f(h4.x));
            h4.y = f2bf(w1); l4.y = f2bf(w1 - b2f(h4.y));
            h4.z = f2bf(w2); l4.z = f2bf(w2 - b2f(h4.z));
            h4.w = f2bf(w3); l4.w = f2bf(w3 - b2f(h4.w));
            *(ushort4*)&wt_hi[gc * 72 + ko] = h4;
            *(ushort4*)&wt_lo[gc * 72 + ko] = l4;
        }
        // ---- b1 update (uses old b1r after B3) ----
        float b1n_ = b1r - (pb[0 * 64 + lane] + pb[1 * 64 + lane] +
                            pb[2 * 64 + lane] + pb[3 * 64 + lane]);
        __syncthreads(); // B3

        // ======== row-major Zbar LN + output ========
        float4 zz2 = *(const float4*)&zbT[lane * 20 + 4 * w];
        float zbr[4] = {zz2.x + b1r, zz2.y + b1r, zz2.z + b1r, zz2.w + b1r};
        #pragma unroll
        for (int r = 0; r < 4; ++r) {
            float s1 = wsum64(zbr[r]);
            float s2 = wsum64(zbr[r] * zbr[r]);
            float mu = s1 * (1.f / 64.f);
            float var = s2 * (1.f / 64.f) - mu * mu;
            float rstd = rsqrtf(var + 1e-6f);
            float o = lnwr * ((zbr[r] - mu) * rstd) + lnbr + xq_rm[r];
            Y[gbase + (size_t)(l0 + 4 * w + r) * Dd + lane] = o;
        }
        b1r = b1n_;
        // no B4: zbar uses zbT; all cross-step LDS hazards are ordered by
        // B2/B3 of this step + B1 of the next step.
    }
}

// ---------------- post layernorm over D + cast to bf16 ----------------
__global__ __launch_bounds__(256) void postnorm_kernel(const float* __restrict__ Y,
                                                       const float* __restrict__ pw,
                                                       const float* __restrict__ pb,
                                                       unsigned short* __restrict__ Yb) {
    int tok = blockIdx.x, t = threadIdx.x;
    const float* row = Y + (size_t)tok * Dd;
    int c0 = t * 4, c1 = 1024 + t * 4;
    float4 v0 = *(const float4*)(row + c0);
    float4 v1 = *(const float4*)(row + c1);
    float s1 = v0.x + v0.y + v0.z + v0.w + v1.x + v1.y + v1.z + v1.w;
    float s2 = v0.x * v0.x + v0.y * v0.y + v0.z * v0.z + v0.w * v0.w +
               v1.x * v1.x + v1.y * v1.y + v1.z * v1.z + v1.w * v1.w;
    s1 = wsum64(s1); s2 = wsum64(s2);
    __shared__ float r1[4], r2[4];
    if ((t & 63) == 0) { r1[t >> 6] = s1; r2[t >> 6] = s2; }
    __syncthreads();
    float S1 = r1[0] + r1[1] + r1[2] + r1[3];
    float S2 = r2[0] + r2[1] + r2[2] + r2[3];
    float mu = S1 * (1.f / 2048.f);
    float var = S2 * (1.f / 2048.f) - mu * mu;
    float rstd = rsqrtf(var + 1e-6f);
    float4 w0 = *(const float4*)(pw + c0), b0 = *(const float4*)(pb + c0);
    float4 w1 = *(const float4*)(pw + c1), b1 = *(const float4*)(pb + c1);
    ushort4 o0, o1;
    o0.x = f2bf((v0.x - mu) * rstd * w0.x + b0.x);
    o0.y = f2bf((v0.y - mu) * rstd * w0.y + b0.y);
    o0.z = f2bf((v0.z - mu) * rstd * w0.z + b0.z);
    o0.w = f2bf((v0.w - mu) * rstd * w0.w + b0.w);
    o1.x = f2bf((v1.x - mu) * rstd * w1.x + b1.x);
    o1.y = f2bf((v1.y - mu) * rstd * w1.y + b1.y);
    o1.z = f2bf((v1.z - mu) * rstd * w1.z + b1.z);
    o1.w = f2bf((v1.w - mu) * rstd * w1.w + b1.w);
    *(ushort4*)(Yb + (size_t)tok * Dd + c0) = o0;
    *(ushort4*)(Yb + (size_t)tok * Dd + c1) = o1;
}

extern "C" void kernel_launch(void* const* d_in, const int* in_sizes, int n_in,
                              void* d_out, int out_size, void* d_ws, size_t ws_size,
                              hipStream_t stream) {
    const float* hs   = (const float*)d_in[0];
    const float* wq_w = (const float*)d_in[1];
    const float* wq_b = (const float*)d_in[2];
    const float* wk_w = (const float*)d_in[3];
    const float* wk_b = (const float*)d_in[4];
    const float* wv_w = (const float*)d_in[5];
    const float* wv_b = (const float*)d_in[6];
    const float* wo_w = (const float*)d_in[7];
    const float* wo_b = (const float*)d_in[8];
    const float* lnw  = (const float*)d_in[9];
    const float* lnb  = (const float*)d_in[10];
    const float* lr_w = (const float*)d_in[11];
    const float* lr_b = (const float*)d_in[12];
    const float* W1   = (const float*)d_in[13];
    const float* b1   = (const float*)d_in[14];
    const float* pnw  = (const float*)d_in[15];
    const float* pnb  = (const float*)d_in[16];
    float* out = (float*)d_out;

    char* ws = (char*)d_ws;
    size_t off = 0;
    auto alloc = [&](size_t bytes) -> void* {
        void* p = ws + off; off += (bytes + 255) & ~(size_t)255; return p;
    };
    unsigned short* hsb = (unsigned short*)alloc((size_t)MTOK * Dd * 2);
    unsigned short* wtb = (unsigned short*)alloc((size_t)Dd * Dd * 2);
    float* XQ = (float*)alloc((size_t)MTOK * Dd * 4);
    float* XK = (float*)alloc((size_t)MTOK * Dd * 4);
    float* XV = (float*)alloc((size_t)MTOK * Dd * 4);
    float* lrbuf = (float*)alloc((size_t)Bb * Hh * Ls * 4);
    float* Y = XQ;                 // safe alias (per-chain row/col ownership; writes trail reads)
    unsigned short* Yb = hsb;      // hsb dead after QKV GEMMs

    dim3 blk(256);
    cast_hs_kernel<<<dim3(MTOK * Dd / 1024), blk, 0, stream>>>(hs, hsb);

    transpose_cast_kernel<<<dim3(1024), blk, 0, stream>>>(wq_w, wtb);
    gemm_bt_kernel<<<dim3(64, 16), blk, 0, stream>>>(hsb, wtb, wq_b, XQ, MTOK, Dd, Dd);
    transpose_cast_kernel<<<dim3(1024), blk, 0, stream>>>(wk_w, wtb);
    gemm_bt_kernel<<<dim3(64, 16), blk, 0, stream>>>(hsb, wtb, wk_b, XK, MTOK, Dd, Dd);
    transpose_cast_kernel<<<dim3(1024), blk, 0, stream>>>(wv_w, wtb);
    gemm_bt_kernel<<<dim3(64, 16), blk, 0, stream>>>(hsb, wtb, wv_b, XV, MTOK, Dd, Dd);

    lr_kernel<<<dim3(MTOK), blk, 0, stream>>>(hs, lr_w, lr_b, lrbuf);

    // fixup fused into scan staging (raw GEMM outputs consumed directly)
    scan_kernel<<<dim3(Bb * Hh), blk, 0, stream>>>(XQ, XK, XV, lrbuf, W1, b1, lnw, lnb, Y);

    postnorm_kernel<<<dim3(MTOK), blk, 0, stream>>>(Y, pnw, pnb, Yb);

    transpose_cast_kernel<<<dim3(1024), blk, 0, stream>>>(wo_w, wtb);
    gemm_bt_kernel<<<dim3(64, 16), blk, 0, stream>>>(Yb, wtb, wo_b, out, MTOK, Dd, Dd);
}